// Round 2
// baseline (168.031 us; speedup 1.0000x reference)
//
#include <hip/hip_runtime.h>

#define LOG2E 1.44269504088896340736f
#define NHID 512
#define BLK  256

// Fused single kernel:
//  - per-block prep: pack {2log2e*w_r, 2log2e*w_th, 2log2e*b1, -2*W2} per unit
//    into LDS, block-reduce S = b2 + sum(W2)
//  - per-point loop over 256 unit-PAIRS sharing one v_rcp per pair:
//      tanh(a) = 1 - 2/(exp2(2log2e*a)+1)
//      contribution pair: acc += rcp(da*db) * (wwa*db + wwb*da)
//  - out = sigmoid(S + acc)
__global__ __launch_bounds__(BLK) void polar_fused(
    const float2* __restrict__ x,
    const float2* __restrict__ W1,   // [512] pairs (w_r, w_th)
    const float*  __restrict__ b1,
    const float*  __restrict__ W2,
    const float*  __restrict__ b2,
    float* __restrict__ out, int N)
{
    __shared__ float4 wp[NHID];
    __shared__ float  red[BLK];

    const int t = threadIdx.x;
    const float c = 2.0f * LOG2E;

    // ---- prep: 2 units per thread ----
    float s_partial = 0.0f;
    #pragma unroll
    for (int j = t; j < NHID; j += BLK) {
        const float2 w  = W1[j];
        const float  w2 = W2[j];
        float4 v;
        v.x = w.x * c;
        v.y = w.y * c;
        v.z = b1[j] * c;
        v.w = -2.0f * w2;
        wp[j] = v;
        s_partial += w2;
    }
    red[t] = s_partial;
    __syncthreads();
    #pragma unroll
    for (int s = BLK / 2; s >= 1; s >>= 1) {
        if (t < s) red[t] += red[t + s];
        __syncthreads();
    }
    const float S = red[0] + b2[0];

    // ---- main: one point per thread ----
    const int i = blockIdx.x * BLK + t;
    if (i < N) {
        const float2 p = x[i];
        const float r  = __builtin_amdgcn_sqrtf(fmaf(p.x, p.x, p.y * p.y));
        const float th = atan2f(p.y, p.x);

        float acc = 0.0f;
        #pragma unroll 8
        for (int j = 0; j < NHID; j += 2) {
            const float4 wa = wp[j];
            const float4 wb = wp[j + 1];
            const float aa = fmaf(wa.x, r, fmaf(wa.y, th, wa.z));
            const float ab = fmaf(wb.x, r, fmaf(wb.y, th, wb.z));
            const float ea = __builtin_amdgcn_exp2f(aa);   // exp(2*a_j)
            const float eb = __builtin_amdgcn_exp2f(ab);
            const float da = ea + 1.0f;
            const float db = eb + 1.0f;
            const float rr = __builtin_amdgcn_rcpf(da * db);
            // wwa/da + wwb/db == rr * (wwa*db + wwb*da)
            acc = fmaf(rr, fmaf(wa.w, db, wb.w * da), acc);
        }
        const float z  = S + acc;                           // pre-sigmoid logit
        const float ez = __builtin_amdgcn_exp2f(-z * LOG2E);
        out[i] = __builtin_amdgcn_rcpf(1.0f + ez);
    }
}

extern "C" void kernel_launch(void* const* d_in, const int* in_sizes, int n_in,
                              void* d_out, int out_size, void* d_ws, size_t ws_size,
                              hipStream_t stream) {
    const float* x  = (const float*)d_in[0];
    const float* W1 = (const float*)d_in[1];
    const float* b1 = (const float*)d_in[2];
    const float* W2 = (const float*)d_in[3];
    const float* b2 = (const float*)d_in[4];
    float* out = (float*)d_out;

    const int N = in_sizes[0] / 2;  // 1,000,000 points

    polar_fused<<<(N + BLK - 1) / BLK, BLK, 0, stream>>>(
        (const float2*)x, (const float2*)W1, b1, W2, b2, out, N);
}